// Round 1
// baseline (116.084 us; speedup 1.0000x reference)
//
#include <hip/hip_runtime.h>
#include <float.h>

#define NPRED 8192
#define NGT   32768
#define NSEG  16
#define SEGLEN (NGT / NSEG)   // 2048
#define BLK 256
#define NPB (NPRED / BLK)     // 32 pred-chunks

// ws layout:
//   [0, NGT*16)                      : float4 gt4[NGT]   = (-2gx, -2gy, -2gz, g2)
//   [NGT*16, +NPRED*NSEG*8)          : float2 part[NPRED*NSEG]  (score, idx-bits)
//   [.., +NPB*8)                     : float2 bsums[NPB]

__global__ void prep_gt_kernel(const float* __restrict__ gt, float4* __restrict__ gt4) {
    int j = blockIdx.x * blockDim.x + threadIdx.x;
    if (j < NGT) {
        float x = gt[j * 6 + 0], y = gt[j * 6 + 1], z = gt[j * 6 + 2];
        gt4[j] = make_float4(-2.0f * x, -2.0f * y, -2.0f * z, x * x + y * y + z * z);
    }
}

__global__ __launch_bounds__(BLK) void argmin_part_kernel(const float* __restrict__ pred,
                                                          const float4* __restrict__ gt4,
                                                          float2* __restrict__ part) {
    int i = blockIdx.x * BLK + threadIdx.x;      // pred point
    int s = blockIdx.y;                           // gt segment
    float px = pred[i * 6 + 0];
    float py = pred[i * 6 + 1];
    float pz = pred[i * 6 + 2];
    float best = FLT_MAX;
    int bidx = 0;
    const int j0 = s * SEGLEN;
    #pragma unroll 8
    for (int j = j0; j < j0 + SEGLEN; ++j) {
        float4 g = gt4[j];                        // wave-uniform address -> scalar load
        float sc = fmaf(g.x, px, fmaf(g.y, py, fmaf(g.z, pz, g.w)));
        if (sc < best) { best = sc; bidx = j; }
    }
    float2 r;
    r.x = best;
    r.y = __int_as_float(bidx);
    part[i * NSEG + s] = r;
}

__global__ __launch_bounds__(BLK) void finalize_kernel(const float* __restrict__ pred,
                                                       const float* __restrict__ gt,
                                                       const float2* __restrict__ part,
                                                       float2* __restrict__ bsums) {
    int i = blockIdx.x * BLK + threadIdx.x;
    float best = FLT_MAX;
    int bidx = 0;
    #pragma unroll
    for (int s = 0; s < NSEG; ++s) {              // ascending: ties pick lowest segment
        float2 r = part[i * NSEG + s];
        if (r.x < best) { best = r.x; bidx = __float_as_int(r.y); }
    }
    const float* g = &gt[(long)bidx * 6];
    float gx = g[0], gy = g[1], gz = g[2];
    float gnx = g[3], gny = g[4], gnz = g[5];
    const float* p = &pred[(long)i * 6];
    float px = p[0], py = p[1], pz = p[2];
    float pnx = p[3], pny = p[4], pnz = p[5];

    float dx = px - gx, dy = py - gy, dz = pz - gz;
    float v1 = dx * dx + dy * dy + dz * dz;       // inlier contribution (sum over 3 dims)

    float pn = sqrtf(pnx * pnx + pny * pny + pnz * pnz);
    float gn = sqrtf(gnx * gnx + gny * gny + gnz * gnz);
    float denom = fmaxf(pn, 1e-4f) * fmaxf(gn, 1e-4f);
    float cosv = (pnx * gnx + pny * gny + pnz * gnz) / denom;
    float v2 = 1.0f - cosv;                       // norm-loss contribution

    // wave reduce (64 lanes) then cross-wave via LDS
    #pragma unroll
    for (int off = 32; off > 0; off >>= 1) {
        v1 += __shfl_down(v1, off);
        v2 += __shfl_down(v2, off);
    }
    __shared__ float s1[BLK / 64];
    __shared__ float s2[BLK / 64];
    int wid = threadIdx.x >> 6;
    if ((threadIdx.x & 63) == 0) { s1[wid] = v1; s2[wid] = v2; }
    __syncthreads();
    if (threadIdx.x == 0) {
        float a = 0.0f, b = 0.0f;
        #pragma unroll
        for (int w = 0; w < BLK / 64; ++w) { a += s1[w]; b += s2[w]; }
        bsums[blockIdx.x] = make_float2(a, b);
    }
}

__global__ void final_reduce_kernel(const float2* __restrict__ bsums, float* __restrict__ out) {
    int t = threadIdx.x;
    float v1 = 0.0f, v2 = 0.0f;
    if (t < NPB) { float2 r = bsums[t]; v1 = r.x; v2 = r.y; }
    #pragma unroll
    for (int off = 32; off > 0; off >>= 1) {
        v1 += __shfl_down(v1, off);
        v2 += __shfl_down(v2, off);
    }
    if (t == 0) out[0] = v1 / (NPRED * 3.0f) + v2 / (float)NPRED;
}

extern "C" void kernel_launch(void* const* d_in, const int* in_sizes, int n_in,
                              void* d_out, int out_size, void* d_ws, size_t ws_size,
                              hipStream_t stream) {
    const float* pred_feat = (const float*)d_in[0];
    const float* gt_data   = (const float*)d_in[3];
    float* out = (float*)d_out;

    char* ws = (char*)d_ws;
    float4* gt4   = (float4*)ws;
    float2* part  = (float2*)(ws + (size_t)NGT * 16);
    float2* bsums = (float2*)(ws + (size_t)NGT * 16 + (size_t)NPRED * NSEG * 8);

    prep_gt_kernel<<<NGT / 256, 256, 0, stream>>>(gt_data, gt4);
    dim3 grid(NPB, NSEG);
    argmin_part_kernel<<<grid, BLK, 0, stream>>>(pred_feat, gt4, part);
    finalize_kernel<<<NPB, BLK, 0, stream>>>(pred_feat, gt_data, part, bsums);
    final_reduce_kernel<<<1, 64, 0, stream>>>(bsums, out);
}

// Round 2
// 52.353 us; speedup vs baseline: 2.2173x; 2.2173x over previous
//
#include <hip/hip_runtime.h>
#include <float.h>

#define NPRED 8192
#define NGT   32768
#define BLK   256
#define P     8
#define NCHUNK (NPRED / (BLK * P))   // 4 pred chunks of 2048
#define NSEG   128
#define SEGLEN (NGT / NSEG)          // 256 == BLK
#define NPB    (NPRED / BLK)         // 32 finalize blocks

// ws layout:
//   [0, NGT*16)            float4 gt4[NGT] = (-2gx,-2gy,-2gz,g2)   512KB
//   [+NGT*16, +NPRED*8)    u64 res[NPRED]  packed (scorekey<<32|idx) 64KB
//   [.., +NPB*8)           float2 bsums[NPB]

__global__ void prep_gt_kernel(const float* __restrict__ gt, float4* __restrict__ gt4) {
    int j = blockIdx.x * blockDim.x + threadIdx.x;
    if (j < NGT) {
        float x = gt[j * 6 + 0], y = gt[j * 6 + 1], z = gt[j * 6 + 2];
        gt4[j] = make_float4(-2.0f * x, -2.0f * y, -2.0f * z, x * x + y * y + z * z);
    }
}

__global__ void init_res_kernel(unsigned long long* __restrict__ res) {
    int i = blockIdx.x * blockDim.x + threadIdx.x;
    if (i < NPRED) res[i] = 0xFFFFFFFFFFFFFFFFull;
}

__device__ __forceinline__ unsigned int fkey(float f) {
    unsigned int u = __float_as_uint(f);
    return u ^ (unsigned int)(((int)u >> 31) | 0x80000000);
}

__global__ __launch_bounds__(BLK) void argmin_kernel(const float* __restrict__ pred,
                                                     const float4* __restrict__ gt4,
                                                     unsigned long long* __restrict__ res) {
    __shared__ float4 tile[SEGLEN];
    const int t = threadIdx.x;
    const int chunk = blockIdx.x;
    const int seg = blockIdx.y;
    const int j0 = seg * SEGLEN;

    tile[t] = gt4[j0 + t];                      // SEGLEN == BLK: one float4/thread

    float px[P], py[P], pz[P], best[P];
    unsigned int bj[P];
    const int pbase = chunk * (BLK * P) + t;
    #pragma unroll
    for (int k = 0; k < P; ++k) {
        const float* p = pred + (size_t)(pbase + k * BLK) * 6;
        px[k] = p[0]; py[k] = p[1]; pz[k] = p[2];
        best[k] = FLT_MAX; bj[k] = 0;
    }
    __syncthreads();

    #pragma unroll 4
    for (int jj = 0; jj < SEGLEN; ++jj) {
        float4 g = tile[jj];                    // uniform addr -> LDS broadcast
        #pragma unroll
        for (int k = 0; k < P; ++k) {
            float sc = fmaf(g.x, px[k], fmaf(g.y, py[k], fmaf(g.z, pz[k], g.w)));
            if (sc < best[k]) { best[k] = sc; bj[k] = (unsigned int)jj; }
        }
    }

    #pragma unroll
    for (int k = 0; k < P; ++k) {
        unsigned long long pk = ((unsigned long long)fkey(best[k]) << 32)
                              | (unsigned long long)(j0 + (int)bj[k]);
        atomicMin(&res[pbase + k * BLK], pk);   // deterministic: order-independent
    }
}

__global__ __launch_bounds__(BLK) void finalize_kernel(const float* __restrict__ pred,
                                                       const float* __restrict__ gt,
                                                       const unsigned long long* __restrict__ res,
                                                       float2* __restrict__ bsums) {
    int i = blockIdx.x * BLK + threadIdx.x;
    int bidx = (int)(res[i] & 0xFFFFFFFFull);

    const float* g = &gt[(size_t)bidx * 6];
    float gx = g[0], gy = g[1], gz = g[2];
    float gnx = g[3], gny = g[4], gnz = g[5];
    const float* p = &pred[(size_t)i * 6];
    float px = p[0], py = p[1], pz = p[2];
    float pnx = p[3], pny = p[4], pnz = p[5];

    float dx = px - gx, dy = py - gy, dz = pz - gz;
    float v1 = dx * dx + dy * dy + dz * dz;

    float pn = sqrtf(pnx * pnx + pny * pny + pnz * pnz);
    float gn = sqrtf(gnx * gnx + gny * gny + gnz * gnz);
    float denom = fmaxf(pn, 1e-4f) * fmaxf(gn, 1e-4f);
    float cosv = (pnx * gnx + pny * gny + pnz * gnz) / denom;
    float v2 = 1.0f - cosv;

    #pragma unroll
    for (int off = 32; off > 0; off >>= 1) {
        v1 += __shfl_down(v1, off);
        v2 += __shfl_down(v2, off);
    }
    __shared__ float s1[BLK / 64];
    __shared__ float s2[BLK / 64];
    int wid = threadIdx.x >> 6;
    if ((threadIdx.x & 63) == 0) { s1[wid] = v1; s2[wid] = v2; }
    __syncthreads();
    if (threadIdx.x == 0) {
        float a = 0.0f, b = 0.0f;
        #pragma unroll
        for (int w = 0; w < BLK / 64; ++w) { a += s1[w]; b += s2[w]; }
        bsums[blockIdx.x] = make_float2(a, b);
    }
}

__global__ void final_reduce_kernel(const float2* __restrict__ bsums, float* __restrict__ out) {
    int t = threadIdx.x;
    float v1 = 0.0f, v2 = 0.0f;
    if (t < NPB) { float2 r = bsums[t]; v1 = r.x; v2 = r.y; }
    #pragma unroll
    for (int off = 32; off > 0; off >>= 1) {
        v1 += __shfl_down(v1, off);
        v2 += __shfl_down(v2, off);
    }
    if (t == 0) out[0] = v1 / (NPRED * 3.0f) + v2 / (float)NPRED;
}

extern "C" void kernel_launch(void* const* d_in, const int* in_sizes, int n_in,
                              void* d_out, int out_size, void* d_ws, size_t ws_size,
                              hipStream_t stream) {
    const float* pred_feat = (const float*)d_in[0];
    const float* gt_data   = (const float*)d_in[3];
    float* out = (float*)d_out;

    char* ws = (char*)d_ws;
    float4* gt4 = (float4*)ws;
    unsigned long long* res = (unsigned long long*)(ws + (size_t)NGT * 16);
    float2* bsums = (float2*)(ws + (size_t)NGT * 16 + (size_t)NPRED * 8);

    prep_gt_kernel<<<NGT / 256, 256, 0, stream>>>(gt_data, gt4);
    init_res_kernel<<<NPRED / 256, 256, 0, stream>>>(res);
    dim3 grid(NCHUNK, NSEG);
    argmin_kernel<<<grid, BLK, 0, stream>>>(pred_feat, gt4, res);
    finalize_kernel<<<NPB, BLK, 0, stream>>>(pred_feat, gt_data, res, bsums);
    final_reduce_kernel<<<1, 64, 0, stream>>>(bsums, out);
}

// Round 3
// 41.337 us; speedup vs baseline: 2.8082x; 1.2665x over previous
//
#include <hip/hip_runtime.h>
#include <float.h>

#define NPRED 8192
#define NGT   32768
#define BLK   256
#define P     8
#define NCHUNK (NPRED / (BLK * P))   // 4 pred chunks of 2048
#define NSEG   128
#define SEGLEN (NGT / NSEG)          // 256 == BLK
#define G      4                     // gt group size (min3 trick)
#define NGRP   (SEGLEN / G)          // 64 groups -> group id fits inline const
#define NPB    (NPRED / BLK)         // 32 finalize blocks

// ws layout:
//   [0, NGT*16)            float4 gt4[NGT] = (-2gx,-2gy,-2gz,g2)   512KB
//   [+NGT*16, +NPRED*8)    u64 res[NPRED]  packed (scorekey<<32|idx) 64KB
//   [.., +NPB*8)           float2 bsums[NPB]

__global__ void prep_kernel(const float* __restrict__ gt, float4* __restrict__ gt4,
                            unsigned long long* __restrict__ res) {
    int j = blockIdx.x * blockDim.x + threadIdx.x;
    if (j < NGT) {
        float x = gt[j * 6 + 0], y = gt[j * 6 + 1], z = gt[j * 6 + 2];
        gt4[j] = make_float4(-2.0f * x, -2.0f * y, -2.0f * z, x * x + y * y + z * z);
    }
    if (j < NPRED) res[j] = 0xFFFFFFFFFFFFFFFFull;
}

__device__ __forceinline__ unsigned int fkey(float f) {
    unsigned int u = __float_as_uint(f);
    return u ^ (unsigned int)(((int)u >> 31) | 0x80000000);
}

__device__ __forceinline__ float score(const float4& g, float px, float py, float pz) {
    // fixed fma chain: bit-exact reproducible at rescan
    return fmaf(g.x, px, fmaf(g.y, py, fmaf(g.z, pz, g.w)));
}

__global__ __launch_bounds__(BLK, 2) void argmin_kernel(const float* __restrict__ pred,
                                                        const float4* __restrict__ gt4,
                                                        unsigned long long* __restrict__ res) {
    __shared__ float4 tile[SEGLEN];
    const int t = threadIdx.x;
    const int chunk = blockIdx.x;
    const int seg = blockIdx.y;
    const int j0 = seg * SEGLEN;

    tile[t] = gt4[j0 + t];                      // SEGLEN == BLK: one float4/thread

    float px[P], py[P], pz[P], best[P];
    int bg[P];                                  // best group id (0..NGRP-1)
    const int pbase = chunk * (BLK * P) + t;
    #pragma unroll
    for (int k = 0; k < P; ++k) {
        const float* p = pred + (size_t)(pbase + k * BLK) * 6;
        px[k] = p[0]; py[k] = p[1]; pz[k] = p[2];
        best[k] = FLT_MAX; bg[k] = 0;
    }
    __syncthreads();

    #pragma unroll 2
    for (int grp = 0; grp < NGRP; ++grp) {
        float4 g0 = tile[grp * G + 0];
        float4 g1 = tile[grp * G + 1];
        float4 g2 = tile[grp * G + 2];
        float4 g3 = tile[grp * G + 3];
        #pragma unroll
        for (int k = 0; k < P; ++k) {
            float s0 = score(g0, px[k], py[k], pz[k]);
            float s1 = score(g1, px[k], py[k], pz[k]);
            float s2 = score(g2, px[k], py[k], pz[k]);
            float s3 = score(g3, px[k], py[k], pz[k]);
            // min of 4: v_min3_f32 + v_min_f32 (2 ops)
            float m = fminf(fminf(fminf(s0, s1), s2), s3);
            if (m < best[k]) { best[k] = m; bg[k] = grp; }   // strict <: earliest group wins
        }
    }

    // rescan winning group: identical fma chain -> bit-exact equality
    #pragma unroll
    for (int k = 0; k < P; ++k) {
        int gb = bg[k] * G;
        float4 g0 = tile[gb + 0];
        float4 g1 = tile[gb + 1];
        float4 g2 = tile[gb + 2];
        float4 g3 = tile[gb + 3];
        float s0 = score(g0, px[k], py[k], pz[k]);
        float s1 = score(g1, px[k], py[k], pz[k]);
        float s2 = score(g2, px[k], py[k], pz[k]);
        int off = (s0 == best[k]) ? 0 : (s1 == best[k]) ? 1 : (s2 == best[k]) ? 2 : 3;
        (void)g3;
        unsigned long long pk = ((unsigned long long)fkey(best[k]) << 32)
                              | (unsigned long long)(j0 + gb + off);
        atomicMin(&res[pbase + k * BLK], pk);   // deterministic: order-independent
    }
}

__global__ __launch_bounds__(BLK) void finalize_kernel(const float* __restrict__ pred,
                                                       const float* __restrict__ gt,
                                                       const unsigned long long* __restrict__ res,
                                                       float2* __restrict__ bsums) {
    int i = blockIdx.x * BLK + threadIdx.x;
    int bidx = (int)(res[i] & 0xFFFFFFFFull);

    const float* g = &gt[(size_t)bidx * 6];
    float gx = g[0], gy = g[1], gz = g[2];
    float gnx = g[3], gny = g[4], gnz = g[5];
    const float* p = &pred[(size_t)i * 6];
    float px = p[0], py = p[1], pz = p[2];
    float pnx = p[3], pny = p[4], pnz = p[5];

    float dx = px - gx, dy = py - gy, dz = pz - gz;
    float v1 = dx * dx + dy * dy + dz * dz;

    float pn = sqrtf(pnx * pnx + pny * pny + pnz * pnz);
    float gn = sqrtf(gnx * gnx + gny * gny + gnz * gnz);
    float denom = fmaxf(pn, 1e-4f) * fmaxf(gn, 1e-4f);
    float cosv = (pnx * gnx + pny * gny + pnz * gnz) / denom;
    float v2 = 1.0f - cosv;

    #pragma unroll
    for (int off = 32; off > 0; off >>= 1) {
        v1 += __shfl_down(v1, off);
        v2 += __shfl_down(v2, off);
    }
    __shared__ float s1[BLK / 64];
    __shared__ float s2[BLK / 64];
    int wid = threadIdx.x >> 6;
    if ((threadIdx.x & 63) == 0) { s1[wid] = v1; s2[wid] = v2; }
    __syncthreads();
    if (threadIdx.x == 0) {
        float a = 0.0f, b = 0.0f;
        #pragma unroll
        for (int w = 0; w < BLK / 64; ++w) { a += s1[w]; b += s2[w]; }
        bsums[blockIdx.x] = make_float2(a, b);
    }
}

__global__ void final_reduce_kernel(const float2* __restrict__ bsums, float* __restrict__ out) {
    int t = threadIdx.x;
    float v1 = 0.0f, v2 = 0.0f;
    if (t < NPB) { float2 r = bsums[t]; v1 = r.x; v2 = r.y; }
    #pragma unroll
    for (int off = 32; off > 0; off >>= 1) {
        v1 += __shfl_down(v1, off);
        v2 += __shfl_down(v2, off);
    }
    if (t == 0) out[0] = v1 / (NPRED * 3.0f) + v2 / (float)NPRED;
}

extern "C" void kernel_launch(void* const* d_in, const int* in_sizes, int n_in,
                              void* d_out, int out_size, void* d_ws, size_t ws_size,
                              hipStream_t stream) {
    const float* pred_feat = (const float*)d_in[0];
    const float* gt_data   = (const float*)d_in[3];
    float* out = (float*)d_out;

    char* ws = (char*)d_ws;
    float4* gt4 = (float4*)ws;
    unsigned long long* res = (unsigned long long*)(ws + (size_t)NGT * 16);
    float2* bsums = (float2*)(ws + (size_t)NGT * 16 + (size_t)NPRED * 8);

    prep_kernel<<<NGT / 256, 256, 0, stream>>>(gt_data, gt4, res);
    dim3 grid(NCHUNK, NSEG);
    argmin_kernel<<<grid, BLK, 0, stream>>>(pred_feat, gt4, res);
    finalize_kernel<<<NPB, BLK, 0, stream>>>(pred_feat, gt_data, res, bsums);
    final_reduce_kernel<<<1, 64, 0, stream>>>(bsums, out);
}